// Round 2
// 259.280 us; speedup vs baseline: 1.0255x; 1.0255x over previous
//
#include <hip/hip_runtime.h>

// RNN: o_t = tanh(relu([x_t, o_{t-1}] @ W1[t] + b1[t]) @ W2[t] + b2[t]), T=30.
// Round-3 design (occupancy round) — resubmit after infra-only failure (the
// round-1 bench died acquiring the MI355X container; kernel never ran):
//  - Round-2 was latency-bound: 61.9KB LDS tile -> 2 blocks/CU -> 8 waves/CU
//    (Occupancy 20%, VALUBusy 53%, HBM 20%). Nothing hides the per-timestep
//    LDS-read -> 20-FMA chain -> tanh -> LDS-write dependency.
//  - M=1 (one batch element per thread), EPB=256, ROW=257: tile = 30*257*4 =
//    30.8KB -> 5 blocks/CU = 20 waves/CU (62.5%). v_pk_fma_f32 is not
//    double-rate on gfx950 (FP32 peak == plain-FMA rate), so dropping the M=2
//    packing costs no VALU cycles while halving the LDS footprint.
//  - ROW=257 (odd): compute-phase b32 reads/writes are stride-1 in banks
//    (conflict-free); scatter/gather pattern lands ~2 lanes/bank (free).
//  - Weights still repacked to float4 {w1x,w1h,b1,w2}[t][j] (+b2 in slot 20),
//    read wave-uniformly -> s_load_dwordx4 on the scalar pipe.
//  - Global I/O coalesced float2 (8B/lane); LDS tile overwritten in place
//    (slot [t][e] holds x before step t, o after) -> one tile for in AND out.
// __launch_bounds__(256,5) caps VGPR so LDS (5 blocks/CU) stays the cap.

#define TS  30
#define HID 20
#define THR 256
#define EPB 256              // elements per block (M=1)
#define ROW 257              // LDS row stride in floats (odd -> bank-clean)

__device__ __forceinline__ float fast_tanh(float y) {
    // tanh(y) = 1 - 2/(exp(2y)+1); correct saturation at +/-inf.
    float e = __expf(2.0f * y);
    return 1.0f - 2.0f * __builtin_amdgcn_rcpf(e + 1.0f);
}

__global__ __launch_bounds__(256) void repack_w(
        const float* __restrict__ W1, const float* __restrict__ b1,
        const float* __restrict__ W2, const float* __restrict__ b2,
        float4* __restrict__ wp) {
    for (int i = threadIdx.x; i < TS * 21; i += 256) {
        const int t = i / 21;
        const int j = i - t * 21;
        float4 v;
        if (j < HID) v = make_float4(W1[t * 40 + j], W1[t * 40 + 20 + j],
                                     b1[t * 20 + j], W2[t * 20 + j]);
        else         v = make_float4(b2[t], 0.f, 0.f, 0.f);
        wp[i] = v;
    }
}

__global__ __launch_bounds__(256, 5) void rnn3(
        const float* __restrict__ x,
        const float4* __restrict__ wp,
        float* __restrict__ out) {
    __shared__ float tile[TS * ROW];
    const int tid = threadIdx.x;
    const size_t gbase = (size_t)blockIdx.x * (EPB * TS);

    // ---- coalesced float2 load + LDS transpose scatter ----
    const float2* xg = reinterpret_cast<const float2*>(x + gbase);
#pragma unroll
    for (int i = 0; i < 15; ++i) {
        const float2 v = xg[i * THR + tid];
        const unsigned f0 = (unsigned)(i * THR + tid) * 2u;
        const unsigned e0 = (f0 * 34953u) >> 20;     // exact f/30 for f < 74898
        const unsigned t0 = f0 - e0 * 30u;
        tile[t0 * ROW + e0] = v.x;
        const unsigned f1 = f0 + 1u;
        const unsigned e1 = (f1 * 34953u) >> 20;
        const unsigned t1 = f1 - e1 * 30u;
        tile[t1 * ROW + e1] = v.y;
    }
    __syncthreads();

    // ---- recurrence: 1 elem per thread, weights via scalar loads ----
    float o = 0.f;
#pragma unroll 1
    for (int t = 0; t < TS; ++t) {
        const float4* wr = wp + t * 21;              // wave-uniform -> s_load
        const float xv = tile[t * ROW + tid];
        float acc = wr[20].x;                        // b2[t]
#pragma unroll
        for (int j = 0; j < HID; ++j) {
            const float4 w = wr[j];                  // s_load_dwordx4
            float h = __builtin_fmaf(o, w.y, w.z);
            h = __builtin_fmaf(xv, w.x, h);
            h = __builtin_fmaxf(h, 0.f);
            acc = __builtin_fmaf(h, w.w, acc);
        }
        o = fast_tanh(acc);
        tile[t * ROW + tid] = o;                     // in-place: x -> o
    }
    __syncthreads();

    // ---- LDS gather + coalesced float2 store ----
    float2* og = reinterpret_cast<float2*>(out + gbase);
#pragma unroll
    for (int i = 0; i < 15; ++i) {
        const unsigned f0 = (unsigned)(i * THR + tid) * 2u;
        const unsigned e0 = (f0 * 34953u) >> 20;
        const unsigned t0 = f0 - e0 * 30u;
        const unsigned f1 = f0 + 1u;
        const unsigned e1 = (f1 * 34953u) >> 20;
        const unsigned t1 = f1 - e1 * 30u;
        float2 v;
        v.x = tile[t0 * ROW + e0];
        v.y = tile[t1 * ROW + e1];
        og[i * THR + tid] = v;
    }
}

extern "C" void kernel_launch(void* const* d_in, const int* in_sizes, int n_in,
                              void* d_out, int out_size, void* d_ws, size_t ws_size,
                              hipStream_t stream) {
    const float* x  = (const float*)d_in[0];
    const float* W1 = (const float*)d_in[1];
    const float* b1 = (const float*)d_in[2];
    const float* W2 = (const float*)d_in[3];
    const float* b2 = (const float*)d_in[4];
    float* out = (float*)d_out;
    float4* wp = (float4*)d_ws;                      // 30*21*16 = 10080 B

    repack_w<<<1, 256, 0, stream>>>(W1, b1, W2, b2, wp);

    const int B = 1048576;
    const int grid = B / EPB;                        // 4096 blocks
    rnn3<<<grid, 256, 0, stream>>>(x, wp, out);
}